// Round 2
// 832.745 us; speedup vs baseline: 1.0513x; 1.0513x over previous
//
#include <hip/hip_runtime.h>
#include <stdint.h>

#define B_ 4
#define N_ 2048
#define H_ 8
#define BH_ 32
#define DIM_ 1024

typedef unsigned short ushort_t;
typedef float f32x4 __attribute__((ext_vector_type(4)));
typedef short bf16x8 __attribute__((ext_vector_type(8)));

__device__ __forceinline__ ushort_t f2bf(float f) {
  uint32_t u = __float_as_uint(f);
  u += 0x7fff + ((u >> 16) & 1);   // RNE
  return (ushort_t)(u >> 16);
}

// async global->LDS, 16B per lane. LDS dest must be wave-uniform base + lane*16.
__device__ __forceinline__ void lds_load16(const void* g, void* l) {
  __builtin_amdgcn_global_load_lds(
      (const __attribute__((address_space(1))) unsigned int*)g,
      (__attribute__((address_space(3))) unsigned int*)l, 16, 0, 0);
}

// ---------------- x f32 -> bf16 ----------------
__global__ void cvt_x_kernel(const float* __restrict__ src, ushort_t* __restrict__ dst) {
  int i = (blockIdx.x * 256 + threadIdx.x) * 4;
  float4 v = *(const float4*)(src + i);
  ushort4 o;
  o.x = f2bf(v.x); o.y = f2bf(v.y); o.z = f2bf(v.z); o.w = f2bf(v.w);
  *(ushort4*)(dst + i) = o;
}

// ---------------- W [R][C] f32 -> WT [C][R] bf16 (generic, used for Wo) -------
__global__ void twT_kernel(const float* __restrict__ src, ushort_t* __restrict__ dst,
                           int R, int C) {
  __shared__ float t[32][33];
  int c0 = blockIdx.x * 32, r0 = blockIdx.y * 32;
  int tx = threadIdx.x, ty = threadIdx.y;  // block (32,8)
#pragma unroll
  for (int i = 0; i < 4; i++)
    t[ty + i * 8][tx] = src[(size_t)(r0 + ty + i * 8) * C + c0 + tx];
  __syncthreads();
#pragma unroll
  for (int i = 0; i < 4; i++)
    dst[(size_t)(c0 + ty + i * 8) * R + r0 + tx] = f2bf(t[tx][ty + i * 8]);
}

// ---------------- Wq/Wk/Wv [1024][512] -> WallT [3*512][1024], one launch -----
__global__ void twT3_kernel(const float* __restrict__ Wq, const float* __restrict__ Wk,
                            const float* __restrict__ Wv, ushort_t* __restrict__ dst) {
  __shared__ float t[32][33];
  const float* src = (blockIdx.z == 0) ? Wq : (blockIdx.z == 1) ? Wk : Wv;
  ushort_t* d = dst + (size_t)blockIdx.z * 512 * 1024;
  int c0 = blockIdx.x * 32, r0 = blockIdx.y * 32;  // C=512, R=1024
  int tx = threadIdx.x, ty = threadIdx.y;          // block (32,8)
#pragma unroll
  for (int i = 0; i < 4; i++)
    t[ty + i * 8][tx] = src[(size_t)(r0 + ty + i * 8) * 512 + c0 + tx];
  __syncthreads();
#pragma unroll
  for (int i = 0; i < 4; i++)
    d[(size_t)(c0 + ty + i * 8) * 1024 + r0 + tx] = f2bf(t[tx][ty + i * 8]);
}

// ---------------- V [bh][n][64] -> Vt [bh][64][n] (bf16) ----------------
__global__ void tv_kernel(const ushort_t* __restrict__ V, ushort_t* __restrict__ Vt) {
  __shared__ ushort_t t[64][65];
  int bh = blockIdx.y, n0 = blockIdx.x * 64;
  int tid = threadIdx.x;  // 256
  const ushort_t* Vh = V + (size_t)bh * N_ * 64;
  ushort_t* Vth = Vt + (size_t)bh * 64 * N_;
#pragma unroll
  for (int i = 0; i < 16; i++) {
    int idx = tid + i * 256;
    int r = idx >> 6, c = idx & 63;
    t[r][c] = Vh[(size_t)(n0 + r) * 64 + c];
  }
  __syncthreads();
#pragma unroll
  for (int i = 0; i < 16; i++) {
    int idx = tid + i * 256;
    int d = idx >> 6, c = idx & 63;
    Vth[(size_t)d * N_ + n0 + c] = t[c][d];
  }
}

// ---------------- bf16 GEMM, 128x128 tile, BK=32, global_load_lds ----------------
// A [M][K] bf16 row-major, BT [Ncols][K] bf16 (i.e. B^T).
// MODE 0: QKV epilogue (cols 0-511 Q*SCALE, 512-1023 K, 1024-1535 V) -> [b,h,n,64] bf16
// MODE 1: out epilogue: f32 + bias -> outp [M][Ncols]
// Launched 1D; XCD-bijective swizzle clusters consecutive output tiles per XCD.
template <int MODE>
__global__ __launch_bounds__(256)
void gemm_bf16_kernel(const ushort_t* __restrict__ A, const ushort_t* __restrict__ BT,
                      int K, int Ncols,
                      ushort_t* __restrict__ qb, ushort_t* __restrict__ kb2,
                      ushort_t* __restrict__ vb,
                      float* __restrict__ outp, const float* __restrict__ bias) {
  __shared__ ushort_t As[128 * 32];   // 8 KB
  __shared__ ushort_t Bs[128 * 32];   // 8 KB
  // XCD swizzle (grid %8 == 0): orig ids are row-major tile order, consecutive on one XCD
  const int cpx = (int)gridDim.x >> 3;
  const int flat = blockIdx.x;
  const int orig = (flat & 7) * cpx + (flat >> 3);
  const int nbx = (MODE == 0) ? 12 : 8;
  const int bx = orig % nbx, by = orig / nbx;
  const int n0 = bx * 128, m0 = by * 128;
  const int tid = threadIdx.x;
  const int lane = tid & 63, wave = tid >> 6;
  const int quad = lane >> 4, l16 = lane & 15;
  const int wm = (wave >> 1) * 64, wn = (wave & 1) * 64;
  f32x4 acc[4][4] = {};
  const int arow = tid >> 2, achk = tid & 3;  // arow 0..63, achk 0..3
  const ushort_t* Ag = A + (size_t)(m0 + arow) * K + achk * 8;
  const ushort_t* Bg = BT + (size_t)(n0 + arow) * K + achk * 8;
  ushort_t* asd = As + tid * 8;
  ushort_t* bsd = Bs + tid * 8;
  const int nk = K >> 5;
  for (int ks = 0; ks < nk; ks++) {
    __syncthreads();
    // full tile = 128 rows x 32 cols x 2B = 8 KB per operand:
    // 256 threads x 16 B covers rows 0..63; second call covers rows 64..127.
    lds_load16(Ag + ks * 32, asd);
    lds_load16(Ag + (size_t)64 * K + ks * 32, asd + 64 * 32);
    lds_load16(Bg + ks * 32, bsd);
    lds_load16(Bg + (size_t)64 * K + ks * 32, bsd + 64 * 32);
    __syncthreads();  // drains vmcnt: staged data visible
    bf16x8 af[4], bfr[4];
#pragma unroll
    for (int i = 0; i < 4; i++)
      af[i] = *(const bf16x8*)(As + (wm + i * 16 + l16) * 32 + quad * 8);
#pragma unroll
    for (int i = 0; i < 4; i++)
      bfr[i] = *(const bf16x8*)(Bs + (wn + i * 16 + l16) * 32 + quad * 8);
#pragma unroll
    for (int i = 0; i < 4; i++)
#pragma unroll
      for (int j = 0; j < 4; j++)
        acc[i][j] = __builtin_amdgcn_mfma_f32_16x16x32_bf16(af[i], bfr[j], acc[i][j], 0, 0, 0);
  }
#pragma unroll
  for (int i = 0; i < 4; i++)
#pragma unroll
    for (int j = 0; j < 4; j++)
#pragma unroll
      for (int r = 0; r < 4; r++) {
        int gm = m0 + wm + i * 16 + quad * 4 + r;
        int gn = n0 + wn + j * 16 + l16;
        float v = acc[i][j][r];
        if (MODE == 0) {
          int b = gm >> 11, n = gm & (N_ - 1);
          int part = gn >> 9;       // uniform per block (128-wide tiles never cross 512)
          int cc = gn & 511;
          int h = cc >> 6, d = cc & 63;
          size_t dst = ((size_t)(b * H_ + h) * N_ + n) * 64 + d;
          if (part == 0) qb[dst] = f2bf(v * 0.125f);
          else if (part == 1) kb2[dst] = f2bf(v);
          else vb[dst] = f2bf(v);
        } else {
          // final output: write-once, never re-read -> non-temporal (keep L2 for others)
          __builtin_nontemporal_store(v + bias[gn], &outp[(size_t)gm * Ncols + gn]);
        }
      }
}

// ---------------- fused attention: S = QK^T, softmax, attn write, O = P V ----------------
// block: 16 Q-rows x full N. 8 waves, wave w owns cols [w*256, w*256+256).
// 1D grid 4096, XCD-swizzled so each XCD owns 4 contiguous bh (K/Vt L2-resident).
#define PCOLS 1032  // 1024 + 8 pad (16B aligned rows)
__global__ __launch_bounds__(512, 4)
void attn_kernel(const ushort_t* __restrict__ Q, const ushort_t* __restrict__ Kb,
                 const ushort_t* __restrict__ Vt, float* __restrict__ attn_out,
                 ushort_t* __restrict__ Ob) {
  __shared__ ushort_t Pl[16 * PCOLS];  // one 1024-col half of P, bf16
  __shared__ float redA[8 * 16];
  __shared__ float redB[8 * 16];
  __shared__ float Ored[4 * 256];
  // swizzle: flat -> orig (bh-major). nwg=4096, cpx=512 -> XCD x owns bh 4x..4x+3
  const int flat = blockIdx.x;
  const int orig = (flat & 7) * 512 + (flat >> 3);
  const int bh = orig >> 7;
  const int q0 = (orig & 127) * 16;
  const int tid = threadIdx.x;
  const int w = tid >> 6, lane = tid & 63, quad = lane >> 4, l16 = lane & 15;

  const ushort_t* Qh = Q + (size_t)bh * N_ * 64;
  const ushort_t* Kh = Kb + (size_t)bh * N_ * 64;
  const ushort_t* Vh = Vt + (size_t)bh * 64 * N_;

  // Q fragments (A-operand, k chunks 0-31 / 32-63)
  bf16x8 qf0 = *(const bf16x8*)(Qh + (size_t)(q0 + l16) * 64 + quad * 8);
  bf16x8 qf1 = *(const bf16x8*)(Qh + (size_t)(q0 + l16) * 64 + 32 + quad * 8);

  // S = Q K^T for this wave's 256 cols: 16 tiles of 16x16
  const int ncol0 = w * 256;
  f32x4 acc[16];
#pragma unroll
  for (int t = 0; t < 16; t++) {
    const ushort_t* kp = Kh + (size_t)(ncol0 + t * 16 + l16) * 64 + quad * 8;
    bf16x8 kf0 = *(const bf16x8*)kp;
    bf16x8 kf1 = *(const bf16x8*)(kp + 32);
    f32x4 z = {};
    z = __builtin_amdgcn_mfma_f32_16x16x32_bf16(qf0, kf0, z, 0, 0, 0);
    acc[t] = __builtin_amdgcn_mfma_f32_16x16x32_bf16(qf1, kf1, z, 0, 0, 0);
  }

  // row max: per-lane over tiles, shuffle over 16-lane col group, LDS across waves
  float mx[4];
#pragma unroll
  for (int r = 0; r < 4; r++) {
    float m = acc[0][r];
#pragma unroll
    for (int t = 1; t < 16; t++) m = fmaxf(m, acc[t][r]);
    for (int off = 1; off < 16; off <<= 1) m = fmaxf(m, __shfl_xor(m, off));
    mx[r] = m;
  }
  if (l16 == 0)
#pragma unroll
    for (int r = 0; r < 4; r++) redA[w * 16 + quad * 4 + r] = mx[r];
  __syncthreads();
#pragma unroll
  for (int r = 0; r < 4; r++) {
    float m = redA[quad * 4 + r];
#pragma unroll
    for (int ww = 1; ww < 8; ww++) m = fmaxf(m, redA[ww * 16 + quad * 4 + r]);
    mx[r] = m;
  }

  // exp + row sum
  float sm[4] = {0.f, 0.f, 0.f, 0.f};
#pragma unroll
  for (int t = 0; t < 16; t++)
#pragma unroll
    for (int r = 0; r < 4; r++) {
      float p = __expf(acc[t][r] - mx[r]);
      acc[t][r] = p;
      sm[r] += p;
    }
#pragma unroll
  for (int r = 0; r < 4; r++) {
    float s = sm[r];
    for (int off = 1; off < 16; off <<= 1) s += __shfl_xor(s, off);
    sm[r] = s;
  }
  if (l16 == 0)
#pragma unroll
    for (int r = 0; r < 4; r++) redB[w * 16 + quad * 4 + r] = sm[r];
  __syncthreads();
  float inv[4];
#pragma unroll
  for (int r = 0; r < 4; r++) {
    float s = 0.f;
#pragma unroll
    for (int ww = 0; ww < 8; ww++) s += redB[ww * 16 + quad * 4 + r];
    inv[r] = 1.0f / s;
  }
#pragma unroll
  for (int t = 0; t < 16; t++)
#pragma unroll
    for (int r = 0; r < 4; r++) acc[t][r] *= inv[r];

  // write normalized attention rows to attn_out (f32), direct scalar stores.
  // Write-once stream (512 MiB total): non-temporal so it doesn't evict K/Vt from L2.
  float* ar = attn_out + ((size_t)bh * N_ + q0) * N_;
#pragma unroll
  for (int t = 0; t < 16; t++) {
    int col = ncol0 + t * 16 + l16;
#pragma unroll
    for (int r = 0; r < 4; r++)
      __builtin_nontemporal_store(acc[t][r], &ar[(size_t)(quad * 4 + r) * N_ + col]);
  }

  // O = P V in two 1024-col phases (P half in LDS as bf16).
  // wave w -> dv tile jt = w&3 ; k-half kh = w>>2 (512 cols per phase)
  const int jt = w & 3, kh = w >> 2;
  f32x4 oacc = {};
  for (int ph = 0; ph < 2; ph++) {
    if (kh == ph) {  // this wave's cols live in this phase's half
#pragma unroll
      for (int t = 0; t < 16; t++) {
        int colb = jt * 256 + t * 16 + l16;
#pragma unroll
        for (int r = 0; r < 4; r++)
          Pl[(quad * 4 + r) * PCOLS + colb] = f2bf(acc[t][r]);
      }
    }
    __syncthreads();
#pragma unroll
    for (int s = 0; s < 16; s++) {
      int klocal = kh * 512 + s * 32;
      bf16x8 pf = *(const bf16x8*)(Pl + l16 * PCOLS + klocal + quad * 8);
      const ushort_t* vp = Vh + (size_t)(jt * 16 + l16) * N_ + ph * 1024 + klocal + quad * 8;
      bf16x8 vf = *(const bf16x8*)vp;
      oacc = __builtin_amdgcn_mfma_f32_16x16x32_bf16(pf, vf, oacc, 0, 0, 0);
    }
    __syncthreads();
  }
  // 2-way cross-wave reduce (waves w and w+4 share tile jt), write Ob [b,n,h*64+d] bf16
  if (w >= 4) {
#pragma unroll
    for (int r = 0; r < 4; r++)
      Ored[jt * 256 + (quad * 4 + r) * 16 + l16] = oacc[r];
  }
  __syncthreads();
  if (w < 4) {
    int b = bh >> 3, h = bh & 7;
#pragma unroll
    for (int r = 0; r < 4; r++) {
      float s = oacc[r] + Ored[jt * 256 + (quad * 4 + r) * 16 + l16];
      Ob[((size_t)(b * N_ + q0 + quad * 4 + r)) * 512 + h * 64 + jt * 16 + l16] = f2bf(s);
    }
  }
}

extern "C" void kernel_launch(void* const* d_in, const int* in_sizes, int n_in,
                              void* d_out, int out_size, void* d_ws, size_t ws_size,
                              hipStream_t stream) {
  const float* x  = (const float*)d_in[0];
  const float* Wq = (const float*)d_in[1];
  const float* Wk = (const float*)d_in[2];
  const float* Wv = (const float*)d_in[3];
  const float* Wo = (const float*)d_in[4];
  const float* bo = (const float*)d_in[5];
  float* outp = (float*)d_out;                         // [4,2048,1024] f32
  float* attnp = outp + (size_t)B_ * N_ * DIM_;        // [4,8,2048,2048] f32

  char* ws = (char*)d_ws;                  // total scratch: 62,914,560 B
  ushort_t* xbf   = (ushort_t*)(ws);                   // 16 MB  [8192][1024] bf16
  ushort_t* WallT = (ushort_t*)(ws + 16777216);        // 3 MB   [1536][1024] bf16 (Wq|Wk|Wv cols)
  ushort_t* WoT   = (ushort_t*)(ws + 19922944);        // 1 MB   [1024][512] bf16
  ushort_t* Qb    = (ushort_t*)(ws + 20971520);        // 8 MB   [bh][n][64] bf16 (scaled)
  ushort_t* Kb    = (ushort_t*)(ws + 29360128);        // 8 MB   [bh][n][64]
  ushort_t* Vb    = (ushort_t*)(ws + 37748736);        // 8 MB   [bh][n][64]
  ushort_t* Vt    = (ushort_t*)(ws + 46137344);        // 8 MB   [bh][64][n]
  ushort_t* Ob    = (ushort_t*)(ws + 54525952);        // 8 MB   [8192][512] bf16

  cvt_x_kernel<<<dim3(8192), dim3(256), 0, stream>>>(x, xbf);
  twT3_kernel<<<dim3(16, 32, 3), dim3(32, 8), 0, stream>>>(Wq, Wk, Wv, WallT);
  twT_kernel<<<dim3(32, 16), dim3(32, 8), 0, stream>>>(Wo, WoT, 512, 1024);

  gemm_bf16_kernel<0><<<dim3(768), dim3(256), 0, stream>>>(
      xbf, WallT, 1024, 1536, Qb, Kb, Vb, nullptr, nullptr);

  tv_kernel<<<dim3(32, 32), dim3(256), 0, stream>>>(Vb, Vt);

  attn_kernel<<<dim3(4096), dim3(512), 0, stream>>>(Qb, Kb, Vt, attnp, Ob);

  gemm_bf16_kernel<1><<<dim3(512), dim3(256), 0, stream>>>(
      Ob, WoT, 512, 1024, nullptr, nullptr, nullptr, outp, bo);
}